// Round 1
// baseline (910.278 us; speedup 1.0000x reference)
//
#include <hip/hip_runtime.h>

#define TPB 256
#define EPT 8
#define CHUNK (TPB * EPT)   // 2048 elements per block
#define NSLICE 64           // histogram slices to spread global atomics

typedef unsigned long long ull;

__device__ __forceinline__ ull shfl_down_u64(ull x, int off) {
    unsigned lo = (unsigned)x, hi = (unsigned)(x >> 32);
    lo = __shfl_down(lo, off, 64);
    hi = __shfl_down(hi, off, 64);
    return ((ull)hi << 32) | lo;
}

// ---------------------------------------------------------------------------
// Pass 1: per-element pre-shift compute + histograms + block sums.
// q64/micro64 in 16 LDS sub-rows; global merge into 64 slices.
// NEW: last-done block performs the old k_pass2 (scan block sums ->
// pos_offset/shift/totalv; sum hist slices; derive wtq7/bits6) in-kernel.
// ---------------------------------------------------------------------------
__global__ __launch_bounds__(TPB, 4) void k_pass1(
    const float* __restrict__ blp, const int* __restrict__ st,
    const int* __restrict__ q, const int* __restrict__ fam,
    const int* __restrict__ mic, const int* __restrict__ vm,
    float* __restrict__ out_structural,
    int* __restrict__ blocksum_v, double* __restrict__ blocksum_c,
    int* __restrict__ ghist, int* __restrict__ counters,
    int* __restrict__ pos_offset, float* __restrict__ shiftp,
    int* __restrict__ totalv_p, float* __restrict__ out_hist, int n)
{
    __shared__ int lh2[2048];    // [0..1023] q64 x 16 rows | [1024..2047] micro64 x 16 rows
    __shared__ int slhs[11];     // 0-3 fam, 4-10 shell
    __shared__ int swv[4];
    __shared__ float swc[4];
    __shared__ int is_last;

    const int tid = threadIdx.x, lane = tid & 63, wave = tid >> 6;
    const long i0 = (long)blockIdx.x * CHUNK + (long)tid * EPT;
    const bool fast = ((long)(blockIdx.x + 1) * CHUNK <= n);

    // ---- loads first: dwordx4 in flight during LDS init + barrier ----
    int stv[9], qv[9], fv[9], micv[8], vmv[8];
    float bpv[8];
    if (fast) {
        const int4 sa = *(const int4*)(st + i0),  sb = *(const int4*)(st + i0 + 4);
        const int4 qa = *(const int4*)(q + i0),   qb = *(const int4*)(q + i0 + 4);
        const int4 fa = *(const int4*)(fam + i0), fb = *(const int4*)(fam + i0 + 4);
        const int4 ma = *(const int4*)(mic + i0), mb = *(const int4*)(mic + i0 + 4);
        const int4 va = *(const int4*)(vm + i0),  vb = *(const int4*)(vm + i0 + 4);
        const float4 ba = *(const float4*)(blp + i0), bb = *(const float4*)(blp + i0 + 4);
        int nst = __shfl_down(sa.x, 1, 64);
        int nq  = __shfl_down(qa.x, 1, 64);
        int nf  = __shfl_down(fa.x, 1, 64);
        if (lane == 63) {
            const long j = i0 + 8;
            nst = (j < n) ? st[j]  : 0;
            nq  = (j < n) ? q[j]   : 0;
            nf  = (j < n) ? fam[j] : 0;
        }
        stv[0]=sa.x; stv[1]=sa.y; stv[2]=sa.z; stv[3]=sa.w; stv[4]=sb.x; stv[5]=sb.y; stv[6]=sb.z; stv[7]=sb.w; stv[8]=nst;
        qv[0]=qa.x;  qv[1]=qa.y;  qv[2]=qa.z;  qv[3]=qa.w;  qv[4]=qb.x;  qv[5]=qb.y;  qv[6]=qb.z;  qv[7]=qb.w;  qv[8]=nq;
        fv[0]=fa.x;  fv[1]=fa.y;  fv[2]=fa.z;  fv[3]=fa.w;  fv[4]=fb.x;  fv[5]=fb.y;  fv[6]=fb.z;  fv[7]=fb.w;  fv[8]=nf;
        micv[0]=ma.x; micv[1]=ma.y; micv[2]=ma.z; micv[3]=ma.w; micv[4]=mb.x; micv[5]=mb.y; micv[6]=mb.z; micv[7]=mb.w;
        vmv[0]=va.x; vmv[1]=va.y; vmv[2]=va.z; vmv[3]=va.w; vmv[4]=vb.x; vmv[5]=vb.y; vmv[6]=vb.z; vmv[7]=vb.w;
        bpv[0]=ba.x; bpv[1]=ba.y; bpv[2]=ba.z; bpv[3]=ba.w; bpv[4]=bb.x; bpv[5]=bb.y; bpv[6]=bb.z; bpv[7]=bb.w;
    } else {
        #pragma unroll
        for (int e = 0; e < 8; ++e) {
            long ii = i0 + e;
            bool r = ii < n;
            stv[e] = r ? st[ii] : 0;  qv[e] = r ? q[ii] : 0;  fv[e] = r ? fam[ii] : 0;
            micv[e] = r ? mic[ii] : 0; vmv[e] = r ? vm[ii] : 0; bpv[e] = r ? blp[ii] : 0.f;
        }
        stv[8] = (i0 + 8 < n) ? st[i0 + 8] : 0;
        qv[8]  = (i0 + 8 < n) ? q[i0 + 8] : 0;
        fv[8]  = (i0 + 8 < n) ? fam[i0 + 8] : 0;
    }

    {   // vectorized LDS zero-init: 8 ints = 2x ds_write_b128 per thread
        int4 z4; z4.x = 0; z4.y = 0; z4.z = 0; z4.w = 0;
        *(int4*)&lh2[tid * 8] = z4;
        *(int4*)&lh2[tid * 8 + 4] = z4;
    }
    if (tid < 11) slhs[tid] = 0;
    __syncthreads();

    const int qrow = ((wave << 2) | (lane & 3)) << 6;        // 16 sub-rows
    int sv = 0;
    float scf = 0.0f;
    ull accF = 0, accS0 = 0, accS1 = 0;
    float structural[8];
    #pragma unroll
    for (int e = 0; e < 8; ++e) {
        int sti = stv[e], qi = qv[e], fi = fv[e], mi = micv[e];
        int v = (vmv[e] != 0);
        int om  = sti & 0xFFF;      int c6  = ((om  >> 6) ^ om ) & 63;
        int omn = stv[e+1] & 0xFFF; int c6n = ((omn >> 6) ^ omn) & 63;
        float d_chi = (float)__popc(c6 ^ c6n) * (1.0f / 6.0f);
        float d_q   = (float)__popc((qi & 63) ^ (qv[e+1] & 63)) * (1.0f / 6.0f);
        int fx = (fi & 3) ^ (fv[e+1] & 3);
        float d_fam = (float)((fx & 1) + ((fx >> 1) & 1)) * 0.5f;
        float score = 0.5f * d_chi + 0.35f * d_q + 0.15f * d_fam;
        score = fminf(fmaxf(score, 1e-6f), 1.0f);
        structural[e] = v ? score : 0.0f;
        float cosine = expf(fminf(bpv[e], 0.0f));
        float combined = 0.5f * (cosine + structural[e]);
        if (v) {
            sv += 1;
            scf += combined;
            atomicAdd(&lh2[qrow + (qi & 63)], 1);
            atomicAdd(&lh2[1024 + qrow + (mi & 63)], 1);
            accF += 1ULL << ((fi & 3) * 16);
            int sh = __popc(c6);
            ull ts = 1ULL << ((sh & 3) * 16);
            if (sh < 4) accS0 += ts; else accS1 += ts;
        }
    }

    if (fast) {
        float4 o;
        o.x=structural[0]; o.y=structural[1]; o.z=structural[2]; o.w=structural[3];
        *(float4*)(out_structural + i0) = o;
        o.x=structural[4]; o.y=structural[5]; o.z=structural[6]; o.w=structural[7];
        *(float4*)(out_structural + i0 + 4) = o;
    } else {
        #pragma unroll
        for (int e = 0; e < 8; ++e)
            if (i0 + e < n) out_structural[i0 + e] = structural[e];
    }

    #pragma unroll
    for (int off = 32; off > 0; off >>= 1) {
        sv  += __shfl_down(sv, off, 64);
        scf += __shfl_down(scf, off, 64);
        accF  += shfl_down_u64(accF, off);
        accS0 += shfl_down_u64(accS0, off);
        accS1 += shfl_down_u64(accS1, off);
    }
    if (lane == 0) {
        swv[wave] = sv; swc[wave] = scf;
        #pragma unroll
        for (int b2 = 0; b2 < 4; ++b2) atomicAdd(&slhs[b2],     (int)((accF  >> (16*b2)) & 0xFFFF));
        #pragma unroll
        for (int b2 = 0; b2 < 4; ++b2) atomicAdd(&slhs[4 + b2], (int)((accS0 >> (16*b2)) & 0xFFFF));
        #pragma unroll
        for (int b2 = 0; b2 < 3; ++b2) atomicAdd(&slhs[8 + b2], (int)((accS1 >> (16*b2)) & 0xFFFF));
    }
    __syncthreads();
    if (tid == 0) {
        blocksum_v[blockIdx.x] = swv[0] + swv[1] + swv[2] + swv[3];
        blocksum_c[blockIdx.x] = (double)swc[0] + (double)swc[1] + (double)swc[2] + (double)swc[3];
    }
    // merge bins 0..138 (139..151 derived in finalize from q_hist64)
    int* gh = ghist + (blockIdx.x & (NSLICE - 1)) * 152;
    for (int t2 = tid; t2 < 139; t2 += TPB) {
        int val;
        if (t2 < 64) {
            val = 0;
            #pragma unroll
            for (int r = 0; r < 16; ++r) val += lh2[(r << 6) + t2];
        } else if (t2 < 68) {
            val = slhs[t2 - 64];
        } else if (t2 < 132) {
            int b2 = t2 - 68;
            val = 0;
            #pragma unroll
            for (int r = 0; r < 16; ++r) val += lh2[1024 + (r << 6) + b2];
        } else {
            val = slhs[4 + (t2 - 132)];
        }
        if (val) atomicAdd(&gh[t2], val);
    }

    // ---- last-done-block finalize (old k_pass2), device-scope handoff ----
    __threadfence();                     // release this block's stores/atomics
    __syncthreads();
    if (tid == 0) is_last = (atomicAdd(&counters[0], 1) == (int)gridDim.x - 1);
    __syncthreads();
    if (!is_last) return;
    __threadfence();                     // acquire all other blocks' results

    // LDS reuse (post-barrier): fin_i = lh2[0..255], fin_d = lh2[256..767], qh = lh2[768..831]
    int* fin_i = lh2;
    double* fin_d = reinterpret_cast<double*>(&lh2[256]);
    int* qh = &lh2[768];
    const int nb = (int)gridDim.x;

    // 1) sum histogram slices -> out_hist[0..138], keep q_hist64 in LDS
    if (tid < 139) {
        int acc = 0;
        #pragma unroll 8
        for (int sl = 0; sl < NSLICE; ++sl) acc += ghist[sl * 152 + tid];
        out_hist[tid] = (float)acc;
        if (tid < 64) qh[tid] = acc;
    }

    // 2) scan block valid counts (8/thread, nb <= 2048) -> pos_offset; sum doubles
    const int base = tid * 8;
    int v8[8]; int run = 0; double drun = 0.0;
    #pragma unroll
    for (int e = 0; e < 8; ++e) {
        int c = base + e;
        v8[e] = run;
        if (c < nb) { run += blocksum_v[c]; drun += blocksum_c[c]; }
    }
    fin_i[tid] = run; fin_d[tid] = drun;
    __syncthreads();
    for (int off = 1; off < TPB; off <<= 1) {
        int y = (tid >= off) ? fin_i[tid - off] : 0;
        __syncthreads();
        fin_i[tid] += y;
        __syncthreads();
    }
    const int excl = fin_i[tid] - run;
    #pragma unroll
    for (int e = 0; e < 8; ++e) {
        int c = base + e;
        if (c < nb) pos_offset[c] = excl + v8[e];
    }
    const int total_v = fin_i[TPB - 1];

    // 3) reduce combined-sum doubles -> shift
    for (int off = TPB / 2; off > 0; off >>= 1) {
        if (tid < off) fin_d[tid] += fin_d[tid + off];
        __syncthreads();
    }
    if (tid == 0) {
        *totalv_p = total_v;
        double vc = (double)(total_v > 1 ? total_v : 1);
        float cur = (float)(fin_d[0] / vc);
        cur = fminf(fmaxf(cur, 1e-4f), 0.9999f);
        float p = fminf(fmaxf(cur, 1e-6f), 0.999999f);
        float lc = logf(p) - log1pf(-p);
        float tgt = (float)(1.0 / 6.0);
        float lt = logf(tgt) - log1pf(-tgt);
        *shiftp = lt - lc;
    }

    // 4) derived bins from q_hist64
    if (tid < 7) {          // q_weight_hist7[w] = sum over bins with popc==w
        int sacc = 0;
        for (int b = 0; b < 64; ++b) if (__popc(b) == tid) sacc += qh[b];
        out_hist[139 + tid] = (float)sacc;
    }
    if (tid < 6) {          // bit_excitation6[j] = sum qh[b]*bit_j(b)
        int sacc = 0;
        for (int b = 0; b < 64; ++b) sacc += qh[b] * ((b >> tid) & 1);
        out_hist[146 + tid] = (float)sacc;
    }
}

// ---------------------------------------------------------------------------
// Pass 3 (fused): recompute combined from structural (>0 iff valid) + blp;
// apply shift -> logp/bmask outputs; in-block run lengths via wave scans;
// per-chunk stats. NEW: last-done block performs the old k_pass4
// (cross-chunk cummax, first-boundary fixup, trailing, patch_count).
// ---------------------------------------------------------------------------
__global__ __launch_bounds__(TPB, 8) void k_pass3(
    const float* __restrict__ strc, const float* __restrict__ blp,
    const float* __restrict__ shiftp, const int* __restrict__ pos_offset,
    float* __restrict__ out_logp, float* __restrict__ out_bmask,
    float* __restrict__ out_len, int* __restrict__ chunk_cnt,
    int* __restrict__ chunk_last, ull* __restrict__ chunk_first,
    int* __restrict__ counters, const int* __restrict__ totalv_p,
    float* __restrict__ out_trailing, float* __restrict__ out_patch, int n)
{
    __shared__ int swt[4], swm[4], scnt[4];
    __shared__ ull sfirst[4];
    __shared__ int sMax[TPB];
    __shared__ int sCnt[TPB];
    __shared__ int is_last;
    const int tid = threadIdx.x, lane = tid & 63, wave = tid >> 6;
    const long i0 = (long)blockIdx.x * CHUNK + (long)tid * EPT;
    const bool fast = ((long)(blockIdx.x + 1) * CHUNK <= n);
    const float shift = *shiftp;

    float sv8[8], bp8[8];
    if (fast) {
        const float4 s0 = *(const float4*)(strc + i0), s1 = *(const float4*)(strc + i0 + 4);
        const float4 p0 = *(const float4*)(blp + i0),  p1 = *(const float4*)(blp + i0 + 4);
        sv8[0]=s0.x; sv8[1]=s0.y; sv8[2]=s0.z; sv8[3]=s0.w; sv8[4]=s1.x; sv8[5]=s1.y; sv8[6]=s1.z; sv8[7]=s1.w;
        bp8[0]=p0.x; bp8[1]=p0.y; bp8[2]=p0.z; bp8[3]=p0.w; bp8[4]=p1.x; bp8[5]=p1.y; bp8[6]=p1.z; bp8[7]=p1.w;
    } else {
        #pragma unroll
        for (int e = 0; e < 8; ++e) {
            long ii = i0 + e;
            bool r = ii < n;
            sv8[e] = r ? strc[ii] : 0.0f;
            bp8[e] = r ? blp[ii] : 0.0f;
        }
    }

    unsigned mv = 0, mb = 0;
    float lp[8], bmf[8], lenv[8];
    #pragma unroll
    for (int e = 0; e < 8; ++e) {
        float s = sv8[e];
        int v = (s > 0.0f);                       // structural clipped >= 1e-6 iff valid
        float cosine = expf(fminf(bp8[e], 0.0f));
        float comb = 0.5f * (cosine + s);
        float p = fminf(fmaxf(comb, 1e-6f), 0.999999f);
        float z = logf(p) - log1pf(-p) + shift;
        float sgm = 1.0f / (1.0f + expf(-z));
        sgm = fminf(fmaxf(sgm, 1e-6f), 0.999999f);
        float clp = logf(sgm);
        lp[e] = clp;
        int bm = (clp >= -0.69314718f) ? 1 : 0;
        bmf[e] = (float)bm;
        mv |= (unsigned)v << e;
        if (bm & v) mb |= 1u << e;
        lenv[e] = 0.0f;
    }
    if (fast) {
        float4 o;
        o.x=lp[0]; o.y=lp[1]; o.z=lp[2]; o.w=lp[3];     *(float4*)(out_logp + i0) = o;
        o.x=lp[4]; o.y=lp[5]; o.z=lp[6]; o.w=lp[7];     *(float4*)(out_logp + i0 + 4) = o;
        o.x=bmf[0]; o.y=bmf[1]; o.z=bmf[2]; o.w=bmf[3]; *(float4*)(out_bmask + i0) = o;
        o.x=bmf[4]; o.y=bmf[5]; o.z=bmf[6]; o.w=bmf[7]; *(float4*)(out_bmask + i0 + 4) = o;
    } else {
        #pragma unroll
        for (int e = 0; e < 8; ++e)
            if (i0 + e < n) { out_logp[i0 + e] = lp[e]; out_bmask[i0 + e] = bmf[e]; }
    }

    // block-wide exclusive valid-count prefix
    int tvc = __popc(mv);
    int x = tvc;
    #pragma unroll
    for (int off = 1; off < 64; off <<= 1) {
        int y = __shfl_up(x, off, 64);
        if (lane >= off) x += y;
    }
    if (lane == 63) swt[wave] = x;
    __syncthreads();
    int wb = pos_offset[blockIdx.x];
    for (int w2 = 0; w2 < wave; ++w2) wb += swt[w2];
    const int vbase = wb + (x - tvc);

    // last-boundary max-scan + cnt/first reductions
    int last = -1;
    if (mb) {
        int hb = 31 - __clz(mb);
        last = vbase + __popc(mv & ((2u << hb) - 1));
    }
    int m = last;
    #pragma unroll
    for (int off = 1; off < 64; off <<= 1) {
        int y = __shfl_up(m, off, 64);
        if (lane >= off && y > m) m = y;
    }
    int exm = __shfl_up(m, 1, 64);
    if (lane == 0) exm = -1;
    if (lane == 63) swm[wave] = m;
    int cnt = __popc(mb);
    ull fp = ~0ULL;
    if (mb) {
        int lb = __ffs(mb) - 1;
        int fv2 = vbase + __popc(mv & ((2u << lb) - 1));
        fp = ((ull)(unsigned)(i0 + lb) << 32) | (unsigned)fv2;
    }
    #pragma unroll
    for (int off = 32; off > 0; off >>= 1) {
        cnt += __shfl_down(cnt, off, 64);
        ull fo = shfl_down_u64(fp, off);
        if (fo < fp) fp = fo;
    }
    if (lane == 0) { scnt[wave] = cnt; sfirst[wave] = fp; }
    __syncthreads();

    int prev = exm;
    for (int w2 = 0; w2 < wave; ++w2) if (swm[w2] > prev) prev = swm[w2];
    int runv = 0;
    #pragma unroll
    for (int e = 0; e < 8; ++e) {
        runv += (mv >> e) & 1;
        if ((mb >> e) & 1) {
            int pos = vbase + runv;
            lenv[e] = (prev >= 0) ? (float)(pos - prev) : 0.0f;  // first-in-chunk fixed by finalize
            prev = pos;
        }
    }
    if (fast) {
        float4 o;
        o.x=lenv[0]; o.y=lenv[1]; o.z=lenv[2]; o.w=lenv[3]; *(float4*)(out_len + i0) = o;
        o.x=lenv[4]; o.y=lenv[5]; o.z=lenv[6]; o.w=lenv[7]; *(float4*)(out_len + i0 + 4) = o;
    } else {
        #pragma unroll
        for (int e = 0; e < 8; ++e)
            if (i0 + e < n) out_len[i0 + e] = lenv[e];
    }
    if (tid == 0) {
        int c = scnt[0] + scnt[1] + scnt[2] + scnt[3];
        int L = swm[0];
        if (swm[1] > L) L = swm[1];
        if (swm[2] > L) L = swm[2];
        if (swm[3] > L) L = swm[3];
        ull F = sfirst[0];
        if (sfirst[1] < F) F = sfirst[1];
        if (sfirst[2] < F) F = sfirst[2];
        if (sfirst[3] < F) F = sfirst[3];
        chunk_cnt[blockIdx.x] = c;
        chunk_last[blockIdx.x] = L > 0 ? L : 0;
        chunk_first[blockIdx.x] = F;
    }

    // ---- last-done-block finalize (old k_pass4), device-scope handoff ----
    __threadfence();                     // release this block's stores
    __syncthreads();
    if (tid == 0) is_last = (atomicAdd(&counters[1], 1) == (int)gridDim.x - 1);
    __syncthreads();
    if (!is_last) return;
    __threadfence();                     // acquire all other blocks' results

    const int nb = (int)gridDim.x;
    const int base = tid * 8;
    int pmax8[8]; int runm = 0; int csum = 0;
    #pragma unroll
    for (int e = 0; e < 8; ++e) {
        int c = base + e;
        pmax8[e] = runm;                 // max of this thread's chunks [base, c)
        if (c < nb) {
            int z = chunk_last[c];       // already >= 0
            if (z > runm) runm = z;
            csum += chunk_cnt[c];
        }
    }
    sMax[tid] = runm; sCnt[tid] = csum;
    __syncthreads();
    for (int off = 1; off < TPB; off <<= 1) {   // inclusive max-scan over threads
        int y = (tid >= off) ? sMax[tid - off] : 0;
        __syncthreads();
        if (y > sMax[tid]) sMax[tid] = y;
        __syncthreads();
    }
    const int exclm = (tid > 0) ? sMax[tid - 1] : 0;
    #pragma unroll
    for (int e = 0; e < 8; ++e) {
        int c = base + e;
        if (c < nb) {
            ull F = chunk_first[c];
            if (F != ~0ULL) {
                int carry = exclm > pmax8[e] ? exclm : pmax8[e];
                int fi = (int)(F >> 32);
                int fv2 = (int)(F & 0xFFFFFFFFu);
                out_len[fi] = (float)(fv2 - carry);
            }
        }
    }
    const int gmax = sMax[TPB - 1];
    for (int off = TPB / 2; off > 0; off >>= 1) {
        if (tid < off) sCnt[tid] += sCnt[tid + off];
        __syncthreads();
    }
    if (tid == 0) {
        int total_v = *totalv_p;
        int trailing = total_v - gmax;
        *out_trailing = (float)trailing;
        *out_patch = (float)(sCnt[0] + (trailing > 0 ? 1 : 0));
    }
}

// ---------------------------------------------------------------------------
extern "C" void kernel_launch(void* const* d_in, const int* in_sizes, int n_in,
                              void* d_out, int out_size, void* d_ws, size_t ws_size,
                              hipStream_t stream)
{
    const float* blp = (const float*)d_in[0];
    const int* st   = (const int*)d_in[1];
    const int* q    = (const int*)d_in[2];
    const int* fam  = (const int*)d_in[3];
    const int* mic  = (const int*)d_in[4];
    const int* vm   = (const int*)d_in[5];
    const int n = in_sizes[0];
    const int nb = (n + CHUNK - 1) / CHUNK;          // 2048 for n=4M

    float* out = (float*)d_out;
    float* out_logp       = out;
    float* out_bmask      = out + (size_t)n;
    float* out_structural = out + 2 * (size_t)n;
    float* out_hist       = out + 3 * (size_t)n;     // 152 floats
    float* out_len        = out + 3 * (size_t)n + 152;
    float* out_trailing   = out + 4 * (size_t)n + 152;
    float* out_patch      = out + 4 * (size_t)n + 153;

    char* w = (char*)d_ws;
    int*    ghist      = (int*)(w);                  // 64 slices x 152 ints (memset)
    int*    counters   = (int*)(w + 38912);          // [0]=k1 done, [1]=k3 done (memset)
    int*    blocksum_v = (int*)(w + 40960);          // nb ints
    int*    pos_offset = (int*)(w + 57344);
    int*    chunk_cnt  = (int*)(w + 73728);
    int*    chunk_last = (int*)(w + 90112);
    float*  shiftp     = (float*)(w + 106496);
    int*    totalv_p   = (int*)(w + 106500);
    double* blocksum_c = (double*)(w + 110592);      // nb doubles
    ull*    chunk_first= (ull*)(w + 131072);         // nb ulls

    hipMemsetAsync(w, 0, NSLICE * 152 * 4 + 8, stream);   // ghist + counters

    k_pass1<<<dim3(nb), dim3(TPB), 0, stream>>>(
        blp, st, q, fam, mic, vm, out_structural,
        blocksum_v, blocksum_c, ghist, counters,
        pos_offset, shiftp, totalv_p, out_hist, n);

    k_pass3<<<dim3(nb), dim3(TPB), 0, stream>>>(
        out_structural, blp, shiftp, pos_offset, out_logp, out_bmask,
        out_len, chunk_cnt, chunk_last, chunk_first,
        counters, totalv_p, out_trailing, out_patch, n);
}

// Round 2
// 193.123 us; speedup vs baseline: 4.7135x; 4.7135x over previous
//
#include <hip/hip_runtime.h>

#define TPB 256
#define EPT 8
#define CHUNK (TPB * EPT)   // 2048 elements per block
#define P2T 1024            // single-block fixup kernel
#define NSLICE 64           // histogram slices to spread global atomics

typedef unsigned long long ull;

__device__ __forceinline__ ull shfl_down_u64(ull x, int off) {
    unsigned lo = (unsigned)x, hi = (unsigned)(x >> 32);
    lo = __shfl_down(lo, off, 64);
    hi = __shfl_down(hi, off, 64);
    return ((ull)hi << 32) | lo;
}

// ---------------------------------------------------------------------------
// Pass 1: per-element pre-shift compute + histograms + block sums.
// q64/micro64 in 16 LDS sub-rows (4 per wave, lane&3); global merge into 64
// slices. Occupancy raised to 8 blocks/CU (latency-limited at 4).
// ---------------------------------------------------------------------------
__global__ __launch_bounds__(TPB, 8) void k_pass1(
    const float* __restrict__ blp, const int* __restrict__ st,
    const int* __restrict__ q, const int* __restrict__ fam,
    const int* __restrict__ mic, const int* __restrict__ vm,
    float* __restrict__ out_structural,
    int* __restrict__ blocksum_v, double* __restrict__ blocksum_c,
    int* __restrict__ ghist, int n)
{
    __shared__ int lh2[2048];    // [0..1023] q64 x 16 rows | [1024..2047] micro64 x 16 rows
    __shared__ int slhs[11];     // 0-3 fam, 4-10 shell
    __shared__ int swv[4];
    __shared__ float swc[4];

    const int tid = threadIdx.x, lane = tid & 63, wave = tid >> 6;
    const long i0 = (long)blockIdx.x * CHUNK + (long)tid * EPT;
    const bool fast = ((long)(blockIdx.x + 1) * CHUNK <= n);

    // ---- loads first: 6 dwordx4 pairs in flight during LDS init + barrier ----
    int stv[9], qv[9], fv[9], micv[8], vmv[8];
    float bpv[8];
    if (fast) {
        const int4 sa = *(const int4*)(st + i0),  sb = *(const int4*)(st + i0 + 4);
        const int4 qa = *(const int4*)(q + i0),   qb = *(const int4*)(q + i0 + 4);
        const int4 fa = *(const int4*)(fam + i0), fb = *(const int4*)(fam + i0 + 4);
        const int4 ma = *(const int4*)(mic + i0), mb = *(const int4*)(mic + i0 + 4);
        const int4 va = *(const int4*)(vm + i0),  vb = *(const int4*)(vm + i0 + 4);
        const float4 ba = *(const float4*)(blp + i0), bb = *(const float4*)(blp + i0 + 4);
        int nst = __shfl_down(sa.x, 1, 64);
        int nq  = __shfl_down(qa.x, 1, 64);
        int nf  = __shfl_down(fa.x, 1, 64);
        if (lane == 63) {
            const long j = i0 + 8;
            nst = (j < n) ? st[j]  : 0;
            nq  = (j < n) ? q[j]   : 0;
            nf  = (j < n) ? fam[j] : 0;
        }
        stv[0]=sa.x; stv[1]=sa.y; stv[2]=sa.z; stv[3]=sa.w; stv[4]=sb.x; stv[5]=sb.y; stv[6]=sb.z; stv[7]=sb.w; stv[8]=nst;
        qv[0]=qa.x;  qv[1]=qa.y;  qv[2]=qa.z;  qv[3]=qa.w;  qv[4]=qb.x;  qv[5]=qb.y;  qv[6]=qb.z;  qv[7]=qb.w;  qv[8]=nq;
        fv[0]=fa.x;  fv[1]=fa.y;  fv[2]=fa.z;  fv[3]=fa.w;  fv[4]=fb.x;  fv[5]=fb.y;  fv[6]=fb.z;  fv[7]=fb.w;  fv[8]=nf;
        micv[0]=ma.x; micv[1]=ma.y; micv[2]=ma.z; micv[3]=ma.w; micv[4]=mb.x; micv[5]=mb.y; micv[6]=mb.z; micv[7]=mb.w;
        vmv[0]=va.x; vmv[1]=va.y; vmv[2]=va.z; vmv[3]=va.w; vmv[4]=vb.x; vmv[5]=vb.y; vmv[6]=vb.z; vmv[7]=vb.w;
        bpv[0]=ba.x; bpv[1]=ba.y; bpv[2]=ba.z; bpv[3]=ba.w; bpv[4]=bb.x; bpv[5]=bb.y; bpv[6]=bb.z; bpv[7]=bb.w;
    } else {
        #pragma unroll
        for (int e = 0; e < 8; ++e) {
            long ii = i0 + e;
            bool r = ii < n;
            stv[e] = r ? st[ii] : 0;  qv[e] = r ? q[ii] : 0;  fv[e] = r ? fam[ii] : 0;
            micv[e] = r ? mic[ii] : 0; vmv[e] = r ? vm[ii] : 0; bpv[e] = r ? blp[ii] : 0.f;
        }
        stv[8] = (i0 + 8 < n) ? st[i0 + 8] : 0;
        qv[8]  = (i0 + 8 < n) ? q[i0 + 8] : 0;
        fv[8]  = (i0 + 8 < n) ? fam[i0 + 8] : 0;
    }

    {   // vectorized LDS zero-init: 8 ints = 2x ds_write_b128 per thread
        int4 z4; z4.x = 0; z4.y = 0; z4.z = 0; z4.w = 0;
        *(int4*)&lh2[tid * 8] = z4;
        *(int4*)&lh2[tid * 8 + 4] = z4;
    }
    if (tid < 11) slhs[tid] = 0;
    __syncthreads();

    const int qrow = ((wave << 2) | (lane & 3)) << 6;        // 16 sub-rows
    int sv = 0;
    float scf = 0.0f;
    ull accF = 0, accS0 = 0, accS1 = 0;
    float structural[8];
    #pragma unroll
    for (int e = 0; e < 8; ++e) {
        int sti = stv[e], qi = qv[e], fi = fv[e], mi = micv[e];
        int v = (vmv[e] != 0);
        int om  = sti & 0xFFF;      int c6  = ((om  >> 6) ^ om ) & 63;
        int omn = stv[e+1] & 0xFFF; int c6n = ((omn >> 6) ^ omn) & 63;
        float d_chi = (float)__popc(c6 ^ c6n) * (1.0f / 6.0f);
        float d_q   = (float)__popc((qi & 63) ^ (qv[e+1] & 63)) * (1.0f / 6.0f);
        int fx = (fi & 3) ^ (fv[e+1] & 3);
        float d_fam = (float)((fx & 1) + ((fx >> 1) & 1)) * 0.5f;
        float score = 0.5f * d_chi + 0.35f * d_q + 0.15f * d_fam;
        score = fminf(fmaxf(score, 1e-6f), 1.0f);
        structural[e] = v ? score : 0.0f;
        float cosine = expf(fminf(bpv[e], 0.0f));
        float combined = 0.5f * (cosine + structural[e]);
        if (v) {
            sv += 1;
            scf += combined;
            atomicAdd(&lh2[qrow + (qi & 63)], 1);
            atomicAdd(&lh2[1024 + qrow + (mi & 63)], 1);
            accF += 1ULL << ((fi & 3) * 16);
            int sh = __popc(c6);
            ull ts = 1ULL << ((sh & 3) * 16);
            if (sh < 4) accS0 += ts; else accS1 += ts;
        }
    }

    if (fast) {
        float4 o;
        o.x=structural[0]; o.y=structural[1]; o.z=structural[2]; o.w=structural[3];
        *(float4*)(out_structural + i0) = o;
        o.x=structural[4]; o.y=structural[5]; o.z=structural[6]; o.w=structural[7];
        *(float4*)(out_structural + i0 + 4) = o;
    } else {
        #pragma unroll
        for (int e = 0; e < 8; ++e)
            if (i0 + e < n) out_structural[i0 + e] = structural[e];
    }

    #pragma unroll
    for (int off = 32; off > 0; off >>= 1) {
        sv  += __shfl_down(sv, off, 64);
        scf += __shfl_down(scf, off, 64);
        accF  += shfl_down_u64(accF, off);
        accS0 += shfl_down_u64(accS0, off);
        accS1 += shfl_down_u64(accS1, off);
    }
    if (lane == 0) {
        swv[wave] = sv; swc[wave] = scf;
        #pragma unroll
        for (int b2 = 0; b2 < 4; ++b2) atomicAdd(&slhs[b2],     (int)((accF  >> (16*b2)) & 0xFFFF));
        #pragma unroll
        for (int b2 = 0; b2 < 4; ++b2) atomicAdd(&slhs[4 + b2], (int)((accS0 >> (16*b2)) & 0xFFFF));
        #pragma unroll
        for (int b2 = 0; b2 < 3; ++b2) atomicAdd(&slhs[8 + b2], (int)((accS1 >> (16*b2)) & 0xFFFF));
    }
    __syncthreads();
    if (tid == 0) {
        blocksum_v[blockIdx.x] = swv[0] + swv[1] + swv[2] + swv[3];
        blocksum_c[blockIdx.x] = (double)swc[0] + (double)swc[1] + (double)swc[2] + (double)swc[3];
    }
    // merge bins 0..138 (139..151 derived later from q_hist64)
    int* gh = ghist + (blockIdx.x & (NSLICE - 1)) * 152;
    for (int t2 = tid; t2 < 139; t2 += TPB) {
        int val;
        if (t2 < 64) {
            val = 0;
            #pragma unroll
            for (int r = 0; r < 16; ++r) val += lh2[(r << 6) + t2];
        } else if (t2 < 68) {
            val = slhs[t2 - 64];
        } else if (t2 < 132) {
            int b2 = t2 - 68;
            val = 0;
            #pragma unroll
            for (int r = 0; r < 16; ++r) val += lh2[1024 + (r << 6) + b2];
        } else {
            val = slhs[4 + (t2 - 132)];
        }
        if (val) atomicAdd(&gh[t2], val);
    }
}

// ---------------------------------------------------------------------------
// Pass 3: recompute combined from structural (>0 iff valid) + blp; apply
// shift -> logp/bmask; in-block run lengths; per-chunk stats.
// NEW: no k_pass2 — each block redundantly reduces the tiny blocksum arrays
// (24 KB, LLC-resident) for its own pos_offset + shift. Block 0 also does
// the histogram finalize as a free tail.
// ---------------------------------------------------------------------------
__global__ __launch_bounds__(TPB, 8) void k_pass3(
    const float* __restrict__ strc, const float* __restrict__ blp,
    const int* __restrict__ bsv, const double* __restrict__ bsc,
    const int* __restrict__ ghist,
    float* __restrict__ out_logp, float* __restrict__ out_bmask,
    float* __restrict__ out_len, int* __restrict__ chunk_cnt,
    int* __restrict__ chunk_last, ull* __restrict__ chunk_first,
    int* __restrict__ totalv_p, float* __restrict__ out_hist, int n)
{
    __shared__ int swt[4], swm[4], scnt[4];
    __shared__ ull sfirst[4];
    __shared__ int sB[4], sT[4];
    __shared__ double sC[4];
    __shared__ int qh[64];
    const int tid = threadIdx.x, lane = tid & 63, wave = tid >> 6;
    const long i0 = (long)blockIdx.x * CHUNK + (long)tid * EPT;
    const bool fast = ((long)(blockIdx.x + 1) * CHUNK <= n);
    const int nb = (int)gridDim.x;

    // ---- issue main loads first; scan below hides under their latency ----
    float sv8[8], bp8[8];
    if (fast) {
        const float4 s0 = *(const float4*)(strc + i0), s1 = *(const float4*)(strc + i0 + 4);
        const float4 p0 = *(const float4*)(blp + i0),  p1 = *(const float4*)(blp + i0 + 4);
        sv8[0]=s0.x; sv8[1]=s0.y; sv8[2]=s0.z; sv8[3]=s0.w; sv8[4]=s1.x; sv8[5]=s1.y; sv8[6]=s1.z; sv8[7]=s1.w;
        bp8[0]=p0.x; bp8[1]=p0.y; bp8[2]=p0.z; bp8[3]=p0.w; bp8[4]=p1.x; bp8[5]=p1.y; bp8[6]=p1.z; bp8[7]=p1.w;
    } else {
        #pragma unroll
        for (int e = 0; e < 8; ++e) {
            long ii = i0 + e;
            bool r = ii < n;
            sv8[e] = r ? strc[ii] : 0.0f;
            bp8[e] = r ? blp[ii] : 0.0f;
        }
    }

    // ---- redundant per-block reduction of blocksum arrays (replaces pass2) ----
    int bsum = 0, tsum = 0;
    double csum = 0.0;
    for (int c = tid; c < nb; c += TPB) {
        int vv = bsv[c];
        tsum += vv;
        if (c < (int)blockIdx.x) bsum += vv;
        csum += bsc[c];
    }
    #pragma unroll
    for (int off = 32; off > 0; off >>= 1) {
        bsum += __shfl_down(bsum, off, 64);
        tsum += __shfl_down(tsum, off, 64);
        csum += __shfl_down(csum, off, 64);
    }
    if (lane == 0) { sB[wave] = bsum; sT[wave] = tsum; sC[wave] = csum; }
    __syncthreads();
    const int wb0     = sB[0] + sB[1] + sB[2] + sB[3];   // exclusive prefix for this block
    const int total_v = sT[0] + sT[1] + sT[2] + sT[3];
    const double dtot = sC[0] + sC[1] + sC[2] + sC[3];
    float shift;
    {
        double vc = (double)(total_v > 1 ? total_v : 1);
        float cur = (float)(dtot / vc);
        cur = fminf(fmaxf(cur, 1e-4f), 0.9999f);
        float p = fminf(fmaxf(cur, 1e-6f), 0.999999f);
        float lc = logf(p) - log1pf(-p);
        float tgt = (float)(1.0 / 6.0);
        float lt = logf(tgt) - log1pf(-tgt);
        shift = lt - lc;
    }

    unsigned mv = 0, mb = 0;
    float lp[8], bmf[8], lenv[8];
    #pragma unroll
    for (int e = 0; e < 8; ++e) {
        float s = sv8[e];
        int v = (s > 0.0f);                       // structural clipped >= 1e-6 iff valid
        float cosine = expf(fminf(bp8[e], 0.0f));
        float comb = 0.5f * (cosine + s);
        float p = fminf(fmaxf(comb, 1e-6f), 0.999999f);
        float z = logf(p) - log1pf(-p) + shift;
        float sgm = 1.0f / (1.0f + expf(-z));
        sgm = fminf(fmaxf(sgm, 1e-6f), 0.999999f);
        float clp = logf(sgm);
        lp[e] = clp;
        int bm = (clp >= -0.69314718f) ? 1 : 0;
        bmf[e] = (float)bm;
        mv |= (unsigned)v << e;
        if (bm & v) mb |= 1u << e;
        lenv[e] = 0.0f;
    }
    if (fast) {
        float4 o;
        o.x=lp[0]; o.y=lp[1]; o.z=lp[2]; o.w=lp[3];     *(float4*)(out_logp + i0) = o;
        o.x=lp[4]; o.y=lp[5]; o.z=lp[6]; o.w=lp[7];     *(float4*)(out_logp + i0 + 4) = o;
        o.x=bmf[0]; o.y=bmf[1]; o.z=bmf[2]; o.w=bmf[3]; *(float4*)(out_bmask + i0) = o;
        o.x=bmf[4]; o.y=bmf[5]; o.z=bmf[6]; o.w=bmf[7]; *(float4*)(out_bmask + i0 + 4) = o;
    } else {
        #pragma unroll
        for (int e = 0; e < 8; ++e)
            if (i0 + e < n) { out_logp[i0 + e] = lp[e]; out_bmask[i0 + e] = bmf[e]; }
    }

    // block-wide exclusive valid-count prefix
    int tvc = __popc(mv);
    int x = tvc;
    #pragma unroll
    for (int off = 1; off < 64; off <<= 1) {
        int y = __shfl_up(x, off, 64);
        if (lane >= off) x += y;
    }
    if (lane == 63) swt[wave] = x;
    __syncthreads();
    int wb = wb0;
    for (int w2 = 0; w2 < wave; ++w2) wb += swt[w2];
    const int vbase = wb + (x - tvc);

    // last-boundary max-scan + cnt/first reductions
    int last = -1;
    if (mb) {
        int hb = 31 - __clz(mb);
        last = vbase + __popc(mv & ((2u << hb) - 1));
    }
    int m = last;
    #pragma unroll
    for (int off = 1; off < 64; off <<= 1) {
        int y = __shfl_up(m, off, 64);
        if (lane >= off && y > m) m = y;
    }
    int exm = __shfl_up(m, 1, 64);
    if (lane == 0) exm = -1;
    if (lane == 63) swm[wave] = m;
    int cnt = __popc(mb);
    ull fp = ~0ULL;
    if (mb) {
        int lb = __ffs(mb) - 1;
        int fv2 = vbase + __popc(mv & ((2u << lb) - 1));
        fp = ((ull)(unsigned)(i0 + lb) << 32) | (unsigned)fv2;
    }
    #pragma unroll
    for (int off = 32; off > 0; off >>= 1) {
        cnt += __shfl_down(cnt, off, 64);
        ull fo = shfl_down_u64(fp, off);
        if (fo < fp) fp = fo;
    }
    if (lane == 0) { scnt[wave] = cnt; sfirst[wave] = fp; }
    __syncthreads();

    int prev = exm;
    for (int w2 = 0; w2 < wave; ++w2) if (swm[w2] > prev) prev = swm[w2];
    int runv = 0;
    #pragma unroll
    for (int e = 0; e < 8; ++e) {
        runv += (mv >> e) & 1;
        if ((mb >> e) & 1) {
            int pos = vbase + runv;
            lenv[e] = (prev >= 0) ? (float)(pos - prev) : 0.0f;  // first-in-chunk fixed by pass4
            prev = pos;
        }
    }
    if (fast) {
        float4 o;
        o.x=lenv[0]; o.y=lenv[1]; o.z=lenv[2]; o.w=lenv[3]; *(float4*)(out_len + i0) = o;
        o.x=lenv[4]; o.y=lenv[5]; o.z=lenv[6]; o.w=lenv[7]; *(float4*)(out_len + i0 + 4) = o;
    } else {
        #pragma unroll
        for (int e = 0; e < 8; ++e)
            if (i0 + e < n) out_len[i0 + e] = lenv[e];
    }
    if (tid == 0) {
        int c = scnt[0] + scnt[1] + scnt[2] + scnt[3];
        int L = swm[0];
        if (swm[1] > L) L = swm[1];
        if (swm[2] > L) L = swm[2];
        if (swm[3] > L) L = swm[3];
        ull F = sfirst[0];
        if (sfirst[1] < F) F = sfirst[1];
        if (sfirst[2] < F) F = sfirst[2];
        if (sfirst[3] < F) F = sfirst[3];
        chunk_cnt[blockIdx.x] = c;
        chunk_last[blockIdx.x] = L > 0 ? L : 0;
        chunk_first[blockIdx.x] = F;
    }

    // ---- block 0 free tail: histogram finalize (reads p1's ghist) ----
    if (blockIdx.x == 0) {
        if (tid < 139) {
            int acc = 0;
            #pragma unroll 8
            for (int sl = 0; sl < NSLICE; ++sl) acc += ghist[sl * 152 + tid];
            out_hist[tid] = (float)acc;
            if (tid < 64) qh[tid] = acc;
        }
        if (tid == 0) *totalv_p = total_v;
        __syncthreads();
        if (tid < 7) {            // q_weight_hist7[w] = sum over bins with popc==w
            int sacc = 0;
            for (int b = 0; b < 64; ++b) if (__popc(b) == tid) sacc += qh[b];
            out_hist[139 + tid] = (float)sacc;
        }
        if (tid < 6) {            // bit_excitation6[j] = sum qh[b]*bit_j(b)
            int sacc = 0;
            for (int b = 0; b < 64; ++b) sacc += qh[b] * ((b >> tid) & 1);
            out_hist[146 + tid] = (float)sacc;
        }
    }
}

// ---------------------------------------------------------------------------
// Pass 4: tiny scan over per-chunk stats -> first-boundary length fix-up,
// trailing, patch_count. 2 chunks/thread, nb <= 2048. Separate kernel so the
// out_len fixup is ordered after all p3 blocks (kernel boundary = cheap flush).
// ---------------------------------------------------------------------------
__global__ __launch_bounds__(P2T) void k_pass4(
    const int* __restrict__ chunk_cnt, const int* __restrict__ chunk_last,
    const ull* __restrict__ chunk_first, const int* __restrict__ totalv_p,
    int nb, float* __restrict__ out_len,
    float* __restrict__ out_trailing, float* __restrict__ out_patch)
{
    __shared__ int s[P2T];
    __shared__ int cs[P2T];
    int t = threadIdx.x;
    int c0 = 2 * t, c1 = 2 * t + 1;
    int a = 0, b = 0;
    if (c0 < nb) { int z = chunk_last[c0]; a = z > 0 ? z : 0; }
    if (c1 < nb) { int z = chunk_last[c1]; b = z > 0 ? z : 0; }
    int cnt = ((c0 < nb) ? chunk_cnt[c0] : 0) + ((c1 < nb) ? chunk_cnt[c1] : 0);
    s[t] = a > b ? a : b;
    cs[t] = cnt;
    __syncthreads();
    for (int off = 1; off < P2T; off <<= 1) {
        int y = (t >= off) ? s[t - off] : 0;
        __syncthreads();
        if (y > s[t]) s[t] = y;
        __syncthreads();
    }
    int excl = (t > 0) ? s[t - 1] : 0;
    int carry0 = excl;
    int carry1 = excl > a ? excl : a;
    if (c0 < nb) {
        ull F = chunk_first[c0];
        if (F != ~0ULL) {
            int fi = (int)(F >> 32);
            int fv2 = (int)(F & 0xFFFFFFFFu);
            out_len[fi] = (float)(fv2 - carry0);
        }
    }
    if (c1 < nb) {
        ull F = chunk_first[c1];
        if (F != ~0ULL) {
            int fi = (int)(F >> 32);
            int fv2 = (int)(F & 0xFFFFFFFFu);
            out_len[fi] = (float)(fv2 - carry1);
        }
    }
    int gmax = s[P2T - 1];
    __syncthreads();
    for (int off = P2T / 2; off > 0; off >>= 1) {
        if (t < off) cs[t] += cs[t + off];
        __syncthreads();
    }
    if (t == 0) {
        int total_v = *totalv_p;
        int trailing = total_v - gmax;
        int patch = cs[0] + (trailing > 0 ? 1 : 0);
        *out_trailing = (float)trailing;
        *out_patch = (float)patch;
    }
}

// ---------------------------------------------------------------------------
extern "C" void kernel_launch(void* const* d_in, const int* in_sizes, int n_in,
                              void* d_out, int out_size, void* d_ws, size_t ws_size,
                              hipStream_t stream)
{
    const float* blp = (const float*)d_in[0];
    const int* st   = (const int*)d_in[1];
    const int* q    = (const int*)d_in[2];
    const int* fam  = (const int*)d_in[3];
    const int* mic  = (const int*)d_in[4];
    const int* vm   = (const int*)d_in[5];
    const int n = in_sizes[0];
    const int nb = (n + CHUNK - 1) / CHUNK;          // 2048 for n=4M

    float* out = (float*)d_out;
    float* out_logp       = out;
    float* out_bmask      = out + (size_t)n;
    float* out_structural = out + 2 * (size_t)n;
    float* out_hist       = out + 3 * (size_t)n;     // 152 floats
    float* out_len        = out + 3 * (size_t)n + 152;
    float* out_trailing   = out + 4 * (size_t)n + 152;
    float* out_patch      = out + 4 * (size_t)n + 153;

    char* w = (char*)d_ws;
    int*    ghist      = (int*)(w);                  // 64 slices x 152 ints (memset)
    int*    blocksum_v = (int*)(w + 40960);          // nb ints
    int*    chunk_cnt  = (int*)(w + 73728);
    int*    chunk_last = (int*)(w + 90112);
    int*    totalv_p   = (int*)(w + 106500);
    double* blocksum_c = (double*)(w + 110592);      // nb doubles
    ull*    chunk_first= (ull*)(w + 131072);         // nb ulls

    hipMemsetAsync(ghist, 0, NSLICE * 152 * 4, stream);

    k_pass1<<<dim3(nb), dim3(TPB), 0, stream>>>(
        blp, st, q, fam, mic, vm, out_structural,
        blocksum_v, blocksum_c, ghist, n);

    k_pass3<<<dim3(nb), dim3(TPB), 0, stream>>>(
        out_structural, blp, blocksum_v, blocksum_c, ghist,
        out_logp, out_bmask, out_len, chunk_cnt, chunk_last, chunk_first,
        totalv_p, out_hist, n);

    k_pass4<<<dim3(1), dim3(P2T), 0, stream>>>(
        chunk_cnt, chunk_last, chunk_first, totalv_p, nb, out_len,
        out_trailing, out_patch);
}

// Round 3
// 192.921 us; speedup vs baseline: 4.7184x; 1.0011x over previous
//
#include <hip/hip_runtime.h>

#define TPB 256
#define EPT 8
#define CHUNK (TPB * EPT)   // 2048 elements per block
#define NSLICE 64           // histogram slices to spread global atomics

typedef unsigned long long ull;
typedef long long ll;

__device__ __forceinline__ ull shfl_down_u64(ull x, int off) {
    unsigned lo = (unsigned)x, hi = (unsigned)(x >> 32);
    lo = __shfl_down(lo, off, 64);
    hi = __shfl_down(hi, off, 64);
    return ((ull)hi << 32) | lo;
}

// ---------------------------------------------------------------------------
// Pass A: per-element pre-shift compute + histograms + block sums.
// Tail: wave 0 does fence-free decoupled lookback (flag+payload in ONE 64-bit
// word via device-scope atomic RMWs -> no __threadfence, no L2 writeback) to
// produce pos_offset[b]; last block computes shift/totalv. Waves 1-3 merge the
// histogram concurrently. All 2048 blocks co-resident (8/CU) -> deadlock-free.
// Word: [63:62]=state(0 inv,1 partial,2 incl) | [61:39]=v_sum | [38:0]=c_fixed
// ---------------------------------------------------------------------------
__global__ __launch_bounds__(TPB, 8) void k_passA(
    const float* __restrict__ blp, const int* __restrict__ st,
    const int* __restrict__ q, const int* __restrict__ fam,
    const int* __restrict__ mic, const int* __restrict__ vm,
    float* __restrict__ out_structural,
    int* __restrict__ ghist, ull* __restrict__ lookA,
    int* __restrict__ pos_offset, float* __restrict__ shiftp,
    int* __restrict__ totalv_p, int n)
{
    __shared__ int lh2[2048];    // [0..1023] q64 x 16 rows | [1024..2047] micro64 x 16 rows
    __shared__ int slhs[11];     // 0-3 fam, 4-10 shell
    __shared__ int swv[4];
    __shared__ float swc[4];

    const int tid = threadIdx.x, lane = tid & 63, wave = tid >> 6;
    const long i0 = (long)blockIdx.x * CHUNK + (long)tid * EPT;
    const bool fast = ((long)(blockIdx.x + 1) * CHUNK <= n);

    // ---- loads first: dwordx4 pairs in flight during LDS init + barrier ----
    int stv[9], qv[9], fv[9], micv[8], vmv[8];
    float bpv[8];
    if (fast) {
        const int4 sa = *(const int4*)(st + i0),  sb = *(const int4*)(st + i0 + 4);
        const int4 qa = *(const int4*)(q + i0),   qb = *(const int4*)(q + i0 + 4);
        const int4 fa = *(const int4*)(fam + i0), fb = *(const int4*)(fam + i0 + 4);
        const int4 ma = *(const int4*)(mic + i0), mb = *(const int4*)(mic + i0 + 4);
        const int4 va = *(const int4*)(vm + i0),  vb = *(const int4*)(vm + i0 + 4);
        const float4 ba = *(const float4*)(blp + i0), bb = *(const float4*)(blp + i0 + 4);
        int nst = __shfl_down(sa.x, 1, 64);
        int nq  = __shfl_down(qa.x, 1, 64);
        int nf  = __shfl_down(fa.x, 1, 64);
        if (lane == 63) {
            const long j = i0 + 8;
            nst = (j < n) ? st[j]  : 0;
            nq  = (j < n) ? q[j]   : 0;
            nf  = (j < n) ? fam[j] : 0;
        }
        stv[0]=sa.x; stv[1]=sa.y; stv[2]=sa.z; stv[3]=sa.w; stv[4]=sb.x; stv[5]=sb.y; stv[6]=sb.z; stv[7]=sb.w; stv[8]=nst;
        qv[0]=qa.x;  qv[1]=qa.y;  qv[2]=qa.z;  qv[3]=qa.w;  qv[4]=qb.x;  qv[5]=qb.y;  qv[6]=qb.z;  qv[7]=qb.w;  qv[8]=nq;
        fv[0]=fa.x;  fv[1]=fa.y;  fv[2]=fa.z;  fv[3]=fa.w;  fv[4]=fb.x;  fv[5]=fb.y;  fv[6]=fb.z;  fv[7]=fb.w;  fv[8]=nf;
        micv[0]=ma.x; micv[1]=ma.y; micv[2]=ma.z; micv[3]=ma.w; micv[4]=mb.x; micv[5]=mb.y; micv[6]=mb.z; micv[7]=mb.w;
        vmv[0]=va.x; vmv[1]=va.y; vmv[2]=va.z; vmv[3]=va.w; vmv[4]=vb.x; vmv[5]=vb.y; vmv[6]=vb.z; vmv[7]=vb.w;
        bpv[0]=ba.x; bpv[1]=ba.y; bpv[2]=ba.z; bpv[3]=ba.w; bpv[4]=bb.x; bpv[5]=bb.y; bpv[6]=bb.z; bpv[7]=bb.w;
    } else {
        #pragma unroll
        for (int e = 0; e < 8; ++e) {
            long ii = i0 + e;
            bool r = ii < n;
            stv[e] = r ? st[ii] : 0;  qv[e] = r ? q[ii] : 0;  fv[e] = r ? fam[ii] : 0;
            micv[e] = r ? mic[ii] : 0; vmv[e] = r ? vm[ii] : 0; bpv[e] = r ? blp[ii] : 0.f;
        }
        stv[8] = (i0 + 8 < n) ? st[i0 + 8] : 0;
        qv[8]  = (i0 + 8 < n) ? q[i0 + 8] : 0;
        fv[8]  = (i0 + 8 < n) ? fam[i0 + 8] : 0;
    }

    {   // vectorized LDS zero-init: 8 ints = 2x ds_write_b128 per thread
        int4 z4; z4.x = 0; z4.y = 0; z4.z = 0; z4.w = 0;
        *(int4*)&lh2[tid * 8] = z4;
        *(int4*)&lh2[tid * 8 + 4] = z4;
    }
    if (tid < 11) slhs[tid] = 0;
    __syncthreads();

    const int qrow = ((wave << 2) | (lane & 3)) << 6;        // 16 sub-rows
    int sv = 0;
    float scf = 0.0f;
    ull accF = 0, accS0 = 0, accS1 = 0;
    float structural[8];
    #pragma unroll
    for (int e = 0; e < 8; ++e) {
        int sti = stv[e], qi = qv[e], fi = fv[e], mi = micv[e];
        int v = (vmv[e] != 0);
        int om  = sti & 0xFFF;      int c6  = ((om  >> 6) ^ om ) & 63;
        int omn = stv[e+1] & 0xFFF; int c6n = ((omn >> 6) ^ omn) & 63;
        float d_chi = (float)__popc(c6 ^ c6n) * (1.0f / 6.0f);
        float d_q   = (float)__popc((qi & 63) ^ (qv[e+1] & 63)) * (1.0f / 6.0f);
        int fx = (fi & 3) ^ (fv[e+1] & 3);
        float d_fam = (float)((fx & 1) + ((fx >> 1) & 1)) * 0.5f;
        float score = 0.5f * d_chi + 0.35f * d_q + 0.15f * d_fam;
        score = fminf(fmaxf(score, 1e-6f), 1.0f);
        structural[e] = v ? score : 0.0f;
        float cosine = expf(fminf(bpv[e], 0.0f));
        float combined = 0.5f * (cosine + structural[e]);
        if (v) {
            sv += 1;
            scf += combined;
            atomicAdd(&lh2[qrow + (qi & 63)], 1);
            atomicAdd(&lh2[1024 + qrow + (mi & 63)], 1);
            accF += 1ULL << ((fi & 3) * 16);
            int sh = __popc(c6);
            ull ts = 1ULL << ((sh & 3) * 16);
            if (sh < 4) accS0 += ts; else accS1 += ts;
        }
    }

    if (fast) {
        float4 o;
        o.x=structural[0]; o.y=structural[1]; o.z=structural[2]; o.w=structural[3];
        *(float4*)(out_structural + i0) = o;
        o.x=structural[4]; o.y=structural[5]; o.z=structural[6]; o.w=structural[7];
        *(float4*)(out_structural + i0 + 4) = o;
    } else {
        #pragma unroll
        for (int e = 0; e < 8; ++e)
            if (i0 + e < n) out_structural[i0 + e] = structural[e];
    }

    #pragma unroll
    for (int off = 32; off > 0; off >>= 1) {
        sv  += __shfl_down(sv, off, 64);
        scf += __shfl_down(scf, off, 64);
        accF  += shfl_down_u64(accF, off);
        accS0 += shfl_down_u64(accS0, off);
        accS1 += shfl_down_u64(accS1, off);
    }
    if (lane == 0) {
        swv[wave] = sv; swc[wave] = scf;
        #pragma unroll
        for (int b2 = 0; b2 < 4; ++b2) atomicAdd(&slhs[b2],     (int)((accF  >> (16*b2)) & 0xFFFF));
        #pragma unroll
        for (int b2 = 0; b2 < 4; ++b2) atomicAdd(&slhs[4 + b2], (int)((accS0 >> (16*b2)) & 0xFFFF));
        #pragma unroll
        for (int b2 = 0; b2 < 3; ++b2) atomicAdd(&slhs[8 + b2], (int)((accS1 >> (16*b2)) & 0xFFFF));
    }
    __syncthreads();

    if (wave != 0) {
        // waves 1-3: global histogram merge, bins 0..138 (139..151 derived in B)
        int t2 = tid - 64;
        if (t2 < 139) {
            int val;
            if (t2 < 64) {
                val = 0;
                #pragma unroll
                for (int r = 0; r < 16; ++r) val += lh2[(r << 6) + t2];
            } else if (t2 < 68) {
                val = slhs[t2 - 64];
            } else if (t2 < 132) {
                int b2 = t2 - 68;
                val = 0;
                #pragma unroll
                for (int r = 0; r < 16; ++r) val += lh2[1024 + (r << 6) + b2];
            } else {
                val = slhs[4 + (t2 - 132)];
            }
            if (val) atomicAdd(&ghist[(blockIdx.x & (NSLICE - 1)) * 152 + t2], val);
        }
    } else {
        // wave 0: decoupled lookback (sum channel), fence-free
        const int b = blockIdx.x;
        const ll lv = (ll)(swv[0] + swv[1] + swv[2] + swv[3]);
        const double lcd = (double)swc[0] + (double)swc[1] + (double)swc[2] + (double)swc[3];
        const ll lcf = (ll)(lcd * 16384.0 + 0.5);
        if (lane == 0)
            atomicExch(&lookA[b], (1ULL << 62) | ((ull)lv << 39) | (ull)lcf);
        ll exV = 0, exC = 0;
        int base = b - 1;
        while (base >= 0) {
            int idx = base - lane;
            ull w; int stt;
            for (;;) {
                w = (idx >= 0) ? atomicAdd(&lookA[idx], 0ULL) : (2ULL << 62);
                stt = (int)(w >> 62);
                if (!__ballot(stt == 0)) break;
                __builtin_amdgcn_s_sleep(1);
            }
            ull incm = __ballot(stt == 2);
            int stop = incm ? (__ffsll((ll)incm) - 1) : 64;
            ll v = 0, c = 0;
            if (lane <= stop && idx >= 0) {
                v = (ll)((w >> 39) & 0x7FFFFFULL);
                c = (ll)(w & 0x7FFFFFFFFFULL);
            }
            #pragma unroll
            for (int off = 32; off > 0; off >>= 1) {
                v += (ll)shfl_down_u64((ull)v, off);
                c += (ll)shfl_down_u64((ull)c, off);
            }
            exV += v; exC += c;       // lane 0 holds the real sums
            if (stop < 64) break;
            base -= 64;
        }
        if (lane == 0) {
            atomicExch(&lookA[b], (2ULL << 62) | ((ull)(exV + lv) << 39) | (ull)(exC + lcf));
            pos_offset[b] = (int)exV;
            if (b == (int)gridDim.x - 1) {
                int tv = (int)(exV + lv);
                *totalv_p = tv;
                double vc = (double)(tv > 1 ? tv : 1);
                float cur = (float)(((double)(exC + lcf) * (1.0 / 16384.0)) / vc);
                cur = fminf(fmaxf(cur, 1e-4f), 0.9999f);
                float p = fminf(fmaxf(cur, 1e-6f), 0.999999f);
                float lc = logf(p) - log1pf(-p);
                float tgt = (float)(1.0 / 6.0);
                float lt = logf(tgt) - log1pf(-tgt);
                *shiftp = lt - lc;
            }
        }
    }
}

// ---------------------------------------------------------------------------
// Pass B: recompute combined from structural (>0 iff valid) + blp; algebraic
// sigmoid  sigmoid(logit(p)+shift) = p/(p+K(1-p)), K=e^-shift  (5 trans -> 2);
// logp/bmask; run lengths with exclusive cross-chunk carry obtained via a
// second lookback channel (max_last / cnt). Last block emits trailing/patch.
// Block 0 finalizes the 152-bin histogram. Replaces old p3 AND p4.
// Word: [63:62]=state | [45:23]=max_last | [22:0]=cnt
// ---------------------------------------------------------------------------
__global__ __launch_bounds__(TPB, 8) void k_passB(
    const float* __restrict__ strc, const float* __restrict__ blp,
    const int* __restrict__ pos_offset, const float* __restrict__ shiftp,
    const int* __restrict__ totalv_p, const int* __restrict__ ghist,
    ull* __restrict__ lookB,
    float* __restrict__ out_logp, float* __restrict__ out_bmask,
    float* __restrict__ out_len, float* __restrict__ out_hist,
    float* __restrict__ out_trailing, float* __restrict__ out_patch, int n)
{
    __shared__ int swt[4], swm[4], scnt[4];
    __shared__ int sCarry;
    __shared__ int qh[64];
    const int tid = threadIdx.x, lane = tid & 63, wave = tid >> 6;
    const long i0 = (long)blockIdx.x * CHUNK + (long)tid * EPT;
    const bool fast = ((long)(blockIdx.x + 1) * CHUNK <= n);

    float sv8[8], bp8[8];
    if (fast) {
        const float4 s0 = *(const float4*)(strc + i0), s1 = *(const float4*)(strc + i0 + 4);
        const float4 p0 = *(const float4*)(blp + i0),  p1 = *(const float4*)(blp + i0 + 4);
        sv8[0]=s0.x; sv8[1]=s0.y; sv8[2]=s0.z; sv8[3]=s0.w; sv8[4]=s1.x; sv8[5]=s1.y; sv8[6]=s1.z; sv8[7]=s1.w;
        bp8[0]=p0.x; bp8[1]=p0.y; bp8[2]=p0.z; bp8[3]=p0.w; bp8[4]=p1.x; bp8[5]=p1.y; bp8[6]=p1.z; bp8[7]=p1.w;
    } else {
        #pragma unroll
        for (int e = 0; e < 8; ++e) {
            long ii = i0 + e;
            bool r = ii < n;
            sv8[e] = r ? strc[ii] : 0.0f;
            bp8[e] = r ? blp[ii] : 0.0f;
        }
    }

    const float shift = *shiftp;             // uniform scalar loads (cheap prologue)
    const int wb0 = pos_offset[blockIdx.x];
    const float K = expf(-shift);

    unsigned mv = 0, mb = 0;
    float lp[8], bmf[8], lenv[8];
    #pragma unroll
    for (int e = 0; e < 8; ++e) {
        float s = sv8[e];
        int v = (s > 0.0f);                  // structural clipped >= 1e-6 iff valid
        float cosine = expf(fminf(bp8[e], 0.0f));
        float comb = 0.5f * (cosine + s);
        float p = fminf(fmaxf(comb, 1e-6f), 0.999999f);
        float d = fmaf(K, 1.0f - p, p);      // p + K(1-p)
        float sgm = p / d;                   // == sigmoid(logit(p)+shift)
        sgm = fminf(fmaxf(sgm, 1e-6f), 0.999999f);
        float clp = logf(sgm);
        lp[e] = clp;
        int bm = (clp >= -0.69314718f) ? 1 : 0;
        bmf[e] = (float)bm;
        mv |= (unsigned)v << e;
        if (bm & v) mb |= 1u << e;
        lenv[e] = 0.0f;
    }
    if (fast) {
        float4 o;
        o.x=lp[0]; o.y=lp[1]; o.z=lp[2]; o.w=lp[3];     *(float4*)(out_logp + i0) = o;
        o.x=lp[4]; o.y=lp[5]; o.z=lp[6]; o.w=lp[7];     *(float4*)(out_logp + i0 + 4) = o;
        o.x=bmf[0]; o.y=bmf[1]; o.z=bmf[2]; o.w=bmf[3]; *(float4*)(out_bmask + i0) = o;
        o.x=bmf[4]; o.y=bmf[5]; o.z=bmf[6]; o.w=bmf[7]; *(float4*)(out_bmask + i0 + 4) = o;
    } else {
        #pragma unroll
        for (int e = 0; e < 8; ++e)
            if (i0 + e < n) { out_logp[i0 + e] = lp[e]; out_bmask[i0 + e] = bmf[e]; }
    }

    // block-wide exclusive valid-count prefix
    int tvc = __popc(mv);
    int x = tvc;
    #pragma unroll
    for (int off = 1; off < 64; off <<= 1) {
        int y = __shfl_up(x, off, 64);
        if (lane >= off) x += y;
    }
    if (lane == 63) swt[wave] = x;
    __syncthreads();
    int wb = wb0;
    for (int w2 = 0; w2 < wave; ++w2) wb += swt[w2];
    const int vbase = wb + (x - tvc);

    // last-boundary max-scan + cnt reduction
    int last = -1;
    if (mb) {
        int hb = 31 - __clz(mb);
        last = vbase + __popc(mv & ((2u << hb) - 1));
    }
    int m = last;
    #pragma unroll
    for (int off = 1; off < 64; off <<= 1) {
        int y = __shfl_up(m, off, 64);
        if (lane >= off && y > m) m = y;
    }
    int exm = __shfl_up(m, 1, 64);
    if (lane == 0) exm = -1;
    if (lane == 63) swm[wave] = m;
    int cnt = __popc(mb);
    #pragma unroll
    for (int off = 32; off > 0; off >>= 1)
        cnt += __shfl_down(cnt, off, 64);
    if (lane == 0) scnt[wave] = cnt;
    __syncthreads();

    // ---- wave 0: lookback (max_last / cnt channel) -> exclusive carry ----
    if (wave == 0) {
        const int b = blockIdx.x;
        int Lown = swm[0];
        if (swm[1] > Lown) Lown = swm[1];
        if (swm[2] > Lown) Lown = swm[2];
        if (swm[3] > Lown) Lown = swm[3];
        if (Lown < 0) Lown = 0;
        const ll Cown = (ll)(scnt[0] + scnt[1] + scnt[2] + scnt[3]);
        if (lane == 0)
            atomicExch(&lookB[b], (1ULL << 62) | ((ull)Lown << 23) | (ull)Cown);
        ll exM = 0, exC = 0;
        int base = b - 1;
        while (base >= 0) {
            int idx = base - lane;
            ull w; int stt;
            for (;;) {
                w = (idx >= 0) ? atomicAdd(&lookB[idx], 0ULL) : (2ULL << 62);
                stt = (int)(w >> 62);
                if (!__ballot(stt == 0)) break;
                __builtin_amdgcn_s_sleep(1);
            }
            ull incm = __ballot(stt == 2);
            int stop = incm ? (__ffsll((ll)incm) - 1) : 64;
            ll mm = 0, c = 0;
            if (lane <= stop && idx >= 0) {
                mm = (ll)((w >> 23) & 0x7FFFFFULL);
                c  = (ll)(w & 0x7FFFFFULL);
            }
            #pragma unroll
            for (int off = 32; off > 0; off >>= 1) {
                ll mo = (ll)shfl_down_u64((ull)mm, off);
                if (mo > mm) mm = mo;
                c += (ll)shfl_down_u64((ull)c, off);
            }
            if (mm > exM) exM = mm;
            exC += c;                        // lane 0 holds the real values
            if (stop < 64) break;
            base -= 64;
        }
        if (lane == 0) {
            ll incM = exM > (ll)Lown ? exM : (ll)Lown;
            atomicExch(&lookB[b], (2ULL << 62) | ((ull)incM << 23) | (ull)(exC + Cown));
            sCarry = (int)exM;
            if (b == (int)gridDim.x - 1) {
                int tv = *totalv_p;
                int trailing = tv - (int)incM;
                *out_trailing = (float)trailing;
                *out_patch = (float)((int)(exC + Cown) + (trailing > 0 ? 1 : 0));
            }
        }
    }
    __syncthreads();

    // run lengths with correct global carry (no fixup pass needed)
    int prev = sCarry;
    if (exm > prev) prev = exm;
    for (int w2 = 0; w2 < wave; ++w2) if (swm[w2] > prev) prev = swm[w2];
    int runv = 0;
    #pragma unroll
    for (int e = 0; e < 8; ++e) {
        runv += (mv >> e) & 1;
        if ((mb >> e) & 1) {
            int pos = vbase + runv;
            lenv[e] = (float)(pos - prev);
            prev = pos;
        }
    }
    if (fast) {
        float4 o;
        o.x=lenv[0]; o.y=lenv[1]; o.z=lenv[2]; o.w=lenv[3]; *(float4*)(out_len + i0) = o;
        o.x=lenv[4]; o.y=lenv[5]; o.z=lenv[6]; o.w=lenv[7]; *(float4*)(out_len + i0 + 4) = o;
    } else {
        #pragma unroll
        for (int e = 0; e < 8; ++e)
            if (i0 + e < n) out_len[i0 + e] = lenv[e];
    }

    // ---- block 0 free tail: histogram finalize ----
    if (blockIdx.x == 0) {
        if (tid < 139) {
            int acc = 0;
            #pragma unroll 8
            for (int sl = 0; sl < NSLICE; ++sl) acc += ghist[sl * 152 + tid];
            out_hist[tid] = (float)acc;
            if (tid < 64) qh[tid] = acc;
        }
        __syncthreads();
        if (tid < 7) {            // q_weight_hist7[w] = sum over bins with popc==w
            int sacc = 0;
            for (int b = 0; b < 64; ++b) if (__popc(b) == tid) sacc += qh[b];
            out_hist[139 + tid] = (float)sacc;
        }
        if (tid < 6) {            // bit_excitation6[j] = sum qh[b]*bit_j(b)
            int sacc = 0;
            for (int b = 0; b < 64; ++b) sacc += qh[b] * ((b >> tid) & 1);
            out_hist[146 + tid] = (float)sacc;
        }
    }
}

// ---------------------------------------------------------------------------
extern "C" void kernel_launch(void* const* d_in, const int* in_sizes, int n_in,
                              void* d_out, int out_size, void* d_ws, size_t ws_size,
                              hipStream_t stream)
{
    const float* blp = (const float*)d_in[0];
    const int* st   = (const int*)d_in[1];
    const int* q    = (const int*)d_in[2];
    const int* fam  = (const int*)d_in[3];
    const int* mic  = (const int*)d_in[4];
    const int* vm   = (const int*)d_in[5];
    const int n = in_sizes[0];
    const int nb = (n + CHUNK - 1) / CHUNK;          // 2048 for n=4M

    float* out = (float*)d_out;
    float* out_logp       = out;
    float* out_bmask      = out + (size_t)n;
    float* out_structural = out + 2 * (size_t)n;
    float* out_hist       = out + 3 * (size_t)n;     // 152 floats
    float* out_len        = out + 3 * (size_t)n + 152;
    float* out_trailing   = out + 4 * (size_t)n + 152;
    float* out_patch      = out + 4 * (size_t)n + 153;

    char* w = (char*)d_ws;
    int*    ghist      = (int*)(w);                  // 64 slices x 152 ints  [memset]
    ull*    lookA      = (ull*)(w + 40960);          // nb x u64              [memset]
    ull*    lookB      = (ull*)(w + 57344);          // nb x u64              [memset]
    int*    pos_offset = (int*)(w + 73728);          // nb ints
    float*  shiftp     = (float*)(w + 81920);
    int*    totalv_p   = (int*)(w + 81924);

    hipMemsetAsync(w, 0, 73728, stream);             // ghist + lookA + lookB

    k_passA<<<dim3(nb), dim3(TPB), 0, stream>>>(
        blp, st, q, fam, mic, vm, out_structural,
        ghist, lookA, pos_offset, shiftp, totalv_p, n);

    k_passB<<<dim3(nb), dim3(TPB), 0, stream>>>(
        out_structural, blp, pos_offset, shiftp, totalv_p, ghist, lookB,
        out_logp, out_bmask, out_len, out_hist, out_trailing, out_patch, n);
}